// Round 5
// baseline (151.100 us; speedup 1.0000x reference)
//
#include <hip/hip_runtime.h>
#include <math.h>

// Problem constants (reference: POS_LEN=32, NUM_F=16, HIDDEN=256, T=32)
#define NUM_F   16
#define FIN     (8 * NUM_F)      // 128 fourier features
#define HIDDEN  256
#define TOUT    32
#define NOFF    63               // distinct offset values: -31..31
#define NPAIRS_TBL (NOFF * NOFF) // 3969
#define PPB     16               // pairs per block (table kernel)
#define NBLK    ((NPAIRS_TBL + PPB - 1) / PPB)   // 249

// ---------------------------------------------------------------------------
// K0: fourier features -> global scratch. feats[pair][f], f = g*16+k.
__global__ __launch_bounds__(256) void gab_feats_kernel(
    const float* __restrict__ freqs, float* __restrict__ feats)
{
    const int e = blockIdx.x * 256 + threadIdx.x;
    if (e >= NPAIRS_TBL * FIN) return;
    const int pair = e >> 7;
    const int f    = e & 127;
    const int g    = f >> 4;
    const float fr = freqs[f & 15];
    const float dr = (float)(pair / NOFF - (NOFF / 2));
    const float dc = (float)(pair % NOFF - (NOFF / 2));
    float base;
    switch (g >> 1) {
        case 0:  base = dr;      break;
        case 1:  base = dc;      break;
        case 2:  base = dr + dc; break;
        default: base = dr - dc; break;
    }
    const float arg = base * fr;
    feats[e] = (g & 1) ? cosf(arg) : sinf(arg);
}

// ---------------------------------------------------------------------------
// KT: table kernel, 249 blocks x 256 threads, 16 pairs/block.
//  - W1 row -> VGPRs via COALESCED 4-round LDS bounce (XOR-swizzled f4 units
//    so the strided row read-back is bank-conflict-free).
//  - layer 1: barrier-free loop over 16 pairs, pure FMA (feats = uniform
//    global loads, 1 cache line per instruction), h -> hbuf[pl][t].
//  - one barrier; layer 2: barrier-free loop, 32-lane broadcast b128 reads
//    of hbuf, shfl_xor(32) merge, wave partials -> part[pl][w][o].
//  - one barrier; final cross-wave reduce, 2 outputs/thread.
__global__ __launch_bounds__(256, 2) void gab_table_kernel(
    const float* __restrict__ feats,
    const float* __restrict__ W1, const float* __restrict__ b1,
    const float* __restrict__ W2, const float* __restrict__ b2,
    float* __restrict__ table)
{
    __shared__ float4 w1s[64 * 32];           // 32 KB staging chunk (swizzled)
    __shared__ float  hbuf[PPB][HIDDEN];      // 16 KB hidden activations
    __shared__ float  part[PPB][4][TOUT];     // 8 KB wave partials

    const int t    = threadIdx.x;
    const int base = blockIdx.x * PPB;                       // block-uniform
    const int npair = (NPAIRS_TBL - base < PPB) ? (NPAIRS_TBL - base) : PPB;

    // ---- W1 row t -> 32 float4 VGPRs, coalesced via LDS bounce ----------
    float4 w1r[32];
    const float4* __restrict__ w1g = (const float4*)W1;      // row r = f4 [32r..32r+31]
    for (int round = 0; round < 4; ++round) {
        // stage rows 64*round..+63 (2048 f4) cooperatively, coalesced
        #pragma unroll
        for (int i = 0; i < 8; ++i) {
            const int flat = i * 256 + t;                    // 0..2047
            const int r = flat >> 5;                         // local row 0..63
            const int c = flat & 31;                         // f4 chunk 0..31
            w1s[r * 32 + (c ^ (r & 7))] = w1g[(round * 64 + r) * 32 + c];
        }
        __syncthreads();
        if ((t >> 6) == round) {                             // owning wave copies
            const int r = t & 63;
            #pragma unroll
            for (int c = 0; c < 32; ++c)
                w1r[c] = w1s[r * 32 + (c ^ (r & 7))];
        }
        __syncthreads();
    }

    // ---- W2 chunk + biases ----------------------------------------------
    const int o = t & 31;                     // output unit
    const int c = t >> 5;                     // k-chunk (0..7) of dot-256
    float4 w2r[8];
    {
        const float4* w2v = (const float4*)(W2 + o * HIDDEN + c * 32);
        #pragma unroll
        for (int k = 0; k < 8; ++k) w2r[k] = w2v[k];
    }
    const float b1t = b1[t];

    // ---- layer 1: all pairs, no barriers ---------------------------------
    for (int pl = 0; pl < npair; ++pl) {
        const float4* __restrict__ fr = (const float4*)(feats + (base + pl) * FIN);
        float a0 = 0.f, a1 = 0.f, a2 = 0.f, a3 = 0.f;
        #pragma unroll
        for (int k = 0; k < 32; k += 2) {
            const float4 fa = fr[k], fb = fr[k + 1];
            a0 = fmaf(w1r[k].x,     fa.x, a0); a1 = fmaf(w1r[k].y,     fa.y, a1);
            a2 = fmaf(w1r[k].z,     fa.z, a2); a3 = fmaf(w1r[k].w,     fa.w, a3);
            a0 = fmaf(w1r[k + 1].x, fb.x, a0); a1 = fmaf(w1r[k + 1].y, fb.y, a1);
            a2 = fmaf(w1r[k + 1].z, fb.z, a2); a3 = fmaf(w1r[k + 1].w, fb.w, a3);
        }
        const float pre = (a0 + a1) + (a2 + a3) + b1t;
        hbuf[pl][t] = pre / (1.0f + expf(-pre));             // SiLU
    }
    __syncthreads();                                         // hbuf ready

    // ---- layer 2: all pairs, no barriers ---------------------------------
    for (int pl = 0; pl < npair; ++pl) {
        const float4* h4 = (const float4*)(&hbuf[pl][c * 32]); // 32-lane bcast
        float s0 = 0.f, s1 = 0.f, s2 = 0.f, s3 = 0.f;
        #pragma unroll
        for (int k = 0; k < 8; k += 2) {
            const float4 ha = h4[k], hb = h4[k + 1];
            s0 = fmaf(w2r[k].x,     ha.x, s0); s1 = fmaf(w2r[k].y,     ha.y, s1);
            s2 = fmaf(w2r[k].z,     ha.z, s2); s3 = fmaf(w2r[k].w,     ha.w, s3);
            s0 = fmaf(w2r[k + 1].x, hb.x, s0); s1 = fmaf(w2r[k + 1].y, hb.y, s1);
            s2 = fmaf(w2r[k + 1].z, hb.z, s2); s3 = fmaf(w2r[k + 1].w, hb.w, s3);
        }
        float s = (s0 + s1) + (s2 + s3);
        s += __shfl_xor(s, 32);               // merge the wave's 2 c-chunks
        if ((t & 63) < 32) part[pl][t >> 6][o] = s;
    }
    __syncthreads();                                         // partials ready

    // ---- final reduce: 512 outputs, 2 per thread --------------------------
    #pragma unroll
    for (int which = 0; which < 2; ++which) {
        const int idx = which * 256 + t;
        const int pl  = idx >> 5;
        const int oo  = idx & 31;
        if (pl < npair) {
            const float r = part[pl][0][oo] + part[pl][1][oo]
                          + part[pl][2][oo] + part[pl][3][oo] + b2[oo];
            table[(base + pl) * TOUT + oo] = r * 0.17677669529663687f; // /sqrt(32)
        }
    }
}

// ---------------------------------------------------------------------------
// Fallback: fully-fused table kernel (used only if ws too small for feats).
__global__ __launch_bounds__(256, 2) void gab_table_fallback(
    const float* __restrict__ freqs,
    const float* __restrict__ W1, const float* __restrict__ b1,
    const float* __restrict__ W2, const float* __restrict__ b2,
    float* __restrict__ table)
{
    __shared__ float feats[FIN];
    __shared__ float hbuf2[HIDDEN];
    __shared__ float part2[4][33];

    const int t = threadIdx.x;
    const int o = t & 31;
    const int c = t >> 5;

    float4 w1r[32];
    {
        const float4* w1v = (const float4*)(W1 + t * FIN);
        #pragma unroll
        for (int k = 0; k < 32; ++k) w1r[k] = w1v[k];
    }
    float4 w2r[8];
    {
        const float4* w2v = (const float4*)(W2 + o * HIDDEN + c * 32);
        #pragma unroll
        for (int k = 0; k < 8; ++k) w2r[k] = w2v[k];
    }
    const float b1t = b1[t];
    const float b2o = b2[o];
    const float myfreq = (t < FIN) ? freqs[t & 15] : 0.0f;

    for (int pp = 0; pp < 8; ++pp) {
        const int pair = blockIdx.x * 8 + pp;
        if (pair >= NPAIRS_TBL) break;
        const float dr = (float)(pair / NOFF - (NOFF / 2));
        const float dc = (float)(pair % NOFF - (NOFF / 2));

        if (t < FIN) {
            const int g = t >> 4;
            float bse;
            switch (g >> 1) {
                case 0:  bse = dr;      break;
                case 1:  bse = dc;      break;
                case 2:  bse = dr + dc; break;
                default: bse = dr - dc; break;
            }
            const float arg = bse * myfreq;
            feats[t] = (g & 1) ? cosf(arg) : sinf(arg);
        }
        __syncthreads();

        float a0 = 0.f, a1 = 0.f, a2 = 0.f, a3 = 0.f;
        const float4* f4 = (const float4*)feats;
        #pragma unroll
        for (int k = 0; k < 32; k += 2) {
            float4 fa = f4[k], fb = f4[k + 1];
            a0 = fmaf(w1r[k].x,     fa.x, a0); a1 = fmaf(w1r[k].y,     fa.y, a1);
            a2 = fmaf(w1r[k].z,     fa.z, a2); a3 = fmaf(w1r[k].w,     fa.w, a3);
            a0 = fmaf(w1r[k + 1].x, fb.x, a0); a1 = fmaf(w1r[k + 1].y, fb.y, a1);
            a2 = fmaf(w1r[k + 1].z, fb.z, a2); a3 = fmaf(w1r[k + 1].w, fb.w, a3);
        }
        const float pre = (a0 + a1) + (a2 + a3) + b1t;
        hbuf2[t] = pre / (1.0f + expf(-pre));
        __syncthreads();

        float s0 = 0.f, s1 = 0.f, s2 = 0.f, s3 = 0.f;
        const float4* h4 = (const float4*)(hbuf2 + c * 32);
        #pragma unroll
        for (int k = 0; k < 8; k += 2) {
            float4 ha = h4[k], hb = h4[k + 1];
            s0 = fmaf(w2r[k].x,     ha.x, s0); s1 = fmaf(w2r[k].y,     ha.y, s1);
            s2 = fmaf(w2r[k].z,     ha.z, s2); s3 = fmaf(w2r[k].w,     ha.w, s3);
            s0 = fmaf(w2r[k + 1].x, hb.x, s0); s1 = fmaf(w2r[k + 1].y, hb.y, s1);
            s2 = fmaf(w2r[k + 1].z, hb.z, s2); s3 = fmaf(w2r[k + 1].w, hb.w, s3);
        }
        float s = (s0 + s1) + (s2 + s3);
        s += __shfl_xor(s, 32);
        if ((t & 63) < 32) part2[t >> 6][o] = s;
        __syncthreads();
        if (t < TOUT) {
            const float r = part2[0][t] + part2[1][t] + part2[2][t] + part2[3][t] + b2o;
            table[pair * TOUT + t] = r * 0.17677669529663687f;
        }
        __syncthreads();
    }
}

// ---------------------------------------------------------------------------
// Gather: dr/dc derived exactly from the flat index; only HBM traffic is the
// 128 MiB coalesced float4 output stream; table stays L2-resident.
__global__ __launch_bounds__(256) void gab_gather_kernel(
    const float* __restrict__ table,
    float4* __restrict__ out, int npairs)
{
    const int total = npairs * 8;
    const int stride = gridDim.x * blockDim.x;
    const float4* __restrict__ tbl4 = (const float4*)table;

    for (int idx = blockIdx.x * blockDim.x + threadIdx.x; idx < total; idx += stride) {
        const int p = idx >> 3;
        const int l = idx & 7;
        const int i = p >> 10;
        const int j = p & 1023;
        const int ir = (i >> 5) - (j >> 5) + (NOFF / 2);
        const int ic = (i & 31) - (j & 31) + (NOFF / 2);
        out[idx] = tbl4[(ir * NOFF + ic) * (TOUT / 4) + l];
    }
}

// ---------------------------------------------------------------------------
extern "C" void kernel_launch(void* const* d_in, const int* in_sizes, int n_in,
                              void* d_out, int out_size, void* d_ws, size_t ws_size,
                              hipStream_t stream) {
    // inputs: 0 seq_len 1 freqs(16) 2 W1(256*128) 3 b1(256) 4 W2(32*256)
    //         5 b2(32) 6 dr(S*S) 7 dc(S*S)
    const float* freqs = (const float*)d_in[1];
    const float* W1    = (const float*)d_in[2];
    const float* b1    = (const float*)d_in[3];
    const float* W2    = (const float*)d_in[4];
    const float* b2    = (const float*)d_in[5];
    float* out = (float*)d_out;

    const int npairs = in_sizes[6];                // S*S = 1024*1024

    // ws layout: [table 508 KB][feats ~2 MB]
    const size_t TBL_B   = (size_t)NPAIRS_TBL * TOUT * 4;
    const size_t FEATS_B = (size_t)NPAIRS_TBL * FIN * 4;
    float* table = (float*)d_ws;

    if (ws_size >= TBL_B + FEATS_B) {
        float* feats = (float*)((char*)d_ws + TBL_B);
        const int e_total = NPAIRS_TBL * FIN;
        gab_feats_kernel<<<(e_total + 255) / 256, 256, 0, stream>>>(freqs, feats);
        gab_table_kernel<<<NBLK, 256, 0, stream>>>(feats, W1, b1, W2, b2, table);
    } else {
        gab_table_fallback<<<(NPAIRS_TBL + 7) / 8, 256, 0, stream>>>(freqs, W1, b1, W2, b2, table);
    }

    gab_gather_kernel<<<2048, 256, 0, stream>>>(table, (float4*)out, npairs);
}

// Round 6
// 41.553 us; speedup vs baseline: 3.6363x; 3.6363x over previous
//
#include <hip/hip_runtime.h>
#include <math.h>

// Problem constants (reference: POS_LEN=32, NUM_F=16, HIDDEN=256, T=32)
#define NUM_F   16
#define FIN     (8 * NUM_F)      // 128 fourier features
#define HIDDEN  256
#define TOUT    32
#define NOFF    63               // distinct offset values: -31..31
#define NSUM    125              // distinct dr+dc / dr-dc values: -62..62
#define NPAIRS_TBL (NOFF * NOFF) // 3969
#define PPB     8                // pairs per block (table kernel)
#define NBLK    ((NPAIRS_TBL + PPB - 1) / PPB)   // 497
#define PROWS   (NOFF + NOFF + NSUM + NSUM)      // 376 rows in P

// ---------------------------------------------------------------------------
// KP: layer-1 separable partials. P[rho][h]:
//   rho   0..62  : Pa(ia)  = W1[:,  0: 32] . [sin(dr f), cos(dr f)]
//   rho  63..125 : Pb(ib)  = W1[:, 32: 64] . [sin(dc f), cos(dc f)]
//   rho 126..250 : Pp(ip)  = W1[:, 64: 96] . [sin(s f),  cos(s f)],  s = dr+dc
//   rho 251..375 : Pm(im)  = W1[:, 96:128] . [sin(d f),  cos(d f)],  d = dr-dc
// One block per row; thread t = hidden unit t (dot-32).
__global__ __launch_bounds__(256) void gab_ptab_kernel(
    const float* __restrict__ freqs, const float* __restrict__ W1,
    float* __restrict__ P)
{
    __shared__ float fv[32];            // feature vector for this row
    const int rho = blockIdx.x;
    int grp, val;
    if (rho < NOFF)            { grp = 0; val = rho - 31; }
    else if (rho < 2 * NOFF)   { grp = 1; val = rho - NOFF - 31; }
    else if (rho < 2 * NOFF + NSUM) { grp = 2; val = rho - 2 * NOFF - 62; }
    else                       { grp = 3; val = rho - 2 * NOFF - NSUM - 62; }

    const int t = threadIdx.x;
    if (t < 32) {
        const float arg = (float)val * freqs[t & 15];
        fv[t] = (t < 16) ? sinf(arg) : cosf(arg);   // [sin(16), cos(16)]
    }
    __syncthreads();

    // dot-32: W1 row t, column block grp*32 .. grp*32+31
    const float4* __restrict__ w4 = (const float4*)(W1 + t * FIN + grp * 32);
    const float4* f4 = (const float4*)fv;           // same-address broadcast
    float a0 = 0.f, a1 = 0.f, a2 = 0.f, a3 = 0.f;
    #pragma unroll
    for (int k = 0; k < 8; k += 2) {
        const float4 wa = w4[k], wb = w4[k + 1];
        const float4 fa = f4[k], fb = f4[k + 1];
        a0 = fmaf(wa.x, fa.x, a0); a1 = fmaf(wa.y, fa.y, a1);
        a2 = fmaf(wa.z, fa.z, a2); a3 = fmaf(wa.w, fa.w, a3);
        a0 = fmaf(wb.x, fb.x, a0); a1 = fmaf(wb.y, fb.y, a1);
        a2 = fmaf(wb.z, fb.z, a2); a3 = fmaf(wb.w, fb.w, a3);
    }
    P[rho * HIDDEN + t] = (a0 + a1) + (a2 + a3);
}

// ---------------------------------------------------------------------------
// KT: table kernel. pre[t] = Pa[ia][t] + Pb[ib][t] + Pp[ia+ib][t]
//                          + Pm[ia-ib+62][t] + b1[t]   (4 coalesced loads)
// then silu -> hbuf -> R2's proven layer-2 (2-way-broadcast LDS reads,
// shfl_xor(32) merge, double-buffered part[], 2 barriers/pair).
// No W1 anywhere; low VGPR, tiny LDS -> high occupancy.
__global__ __launch_bounds__(256) void gab_table_kernel(
    const float* __restrict__ P, const float* __restrict__ b1,
    const float* __restrict__ W2, const float* __restrict__ b2,
    float* __restrict__ table)
{
    __shared__ float hbuf[HIDDEN];
    __shared__ float part[2][4][33];

    const int t = threadIdx.x;
    const int o = t & 31;               // output unit
    const int c = t >> 5;               // k-chunk of dot-256

    float4 w2r[8];                      // W2[o][c*32 .. c*32+31]
    {
        const float4* w2v = (const float4*)(W2 + o * HIDDEN + c * 32);
        #pragma unroll
        for (int k = 0; k < 8; ++k) w2r[k] = w2v[k];
    }
    const float b1t = b1[t];
    const float b2o = b2[o];

    const float* __restrict__ Pa = P;
    const float* __restrict__ Pb = P + NOFF * HIDDEN;
    const float* __restrict__ Pp = P + 2 * NOFF * HIDDEN;
    const float* __restrict__ Pm = P + (2 * NOFF + NSUM) * HIDDEN;

    for (int pp = 0; pp < PPB; ++pp) {
        const int pair = blockIdx.x * PPB + pp;   // block-uniform
        if (pair >= NPAIRS_TBL) break;            // uniform break, barrier-safe
        const int ia = pair / NOFF;               // dr + 31
        const int ib = pair % NOFF;               // dc + 31
        const int ip = ia + ib;                   // (dr+dc) + 62
        const int im = ia - ib + 62;              // (dr-dc) + 62

        // layer 1: 4 coalesced row loads + adds
        const float pre = Pa[ia * HIDDEN + t] + Pb[ib * HIDDEN + t]
                        + Pp[ip * HIDDEN + t] + Pm[im * HIDDEN + t] + b1t;
        hbuf[t] = pre / (1.0f + expf(-pre));      // SiLU
        __syncthreads();                          // hbuf write -> read

        // layer 2: thread (o,c) dots 32 of 256 (2-way broadcast reads: free)
        const float4* h4 = (const float4*)(&hbuf[c * 32]);
        float s0 = 0.f, s1 = 0.f, s2 = 0.f, s3 = 0.f;
        #pragma unroll
        for (int k = 0; k < 8; k += 2) {
            const float4 ha = h4[k], hb = h4[k + 1];
            s0 = fmaf(w2r[k].x,     ha.x, s0); s1 = fmaf(w2r[k].y,     ha.y, s1);
            s2 = fmaf(w2r[k].z,     ha.z, s2); s3 = fmaf(w2r[k].w,     ha.w, s3);
            s0 = fmaf(w2r[k + 1].x, hb.x, s0); s1 = fmaf(w2r[k + 1].y, hb.y, s1);
            s2 = fmaf(w2r[k + 1].z, hb.z, s2); s3 = fmaf(w2r[k + 1].w, hb.w, s3);
        }
        float s = (s0 + s1) + (s2 + s3);
        s += __shfl_xor(s, 32);                   // merge the wave's 2 c-chunks
        if ((t & 63) < 32) part[pp & 1][t >> 6][o] = s;
        __syncthreads();                          // part write -> read

        if (t < TOUT) {
            const float r = part[pp & 1][0][t] + part[pp & 1][1][t]
                          + part[pp & 1][2][t] + part[pp & 1][3][t] + b2o;
            table[pair * TOUT + t] = r * 0.17677669529663687f; // * 1/sqrt(32)
        }
        // safe: next pair's hbuf/part writes are to hbuf (all readers done
        // before barrier 2) and part[(pp+1)&1] (other buffer).
    }
}

// ---------------------------------------------------------------------------
// Fallback: R2's fully-fused table kernel (used only if ws too small).
__global__ __launch_bounds__(256, 2) void gab_table_fallback(
    const float* __restrict__ freqs,
    const float* __restrict__ W1, const float* __restrict__ b1,
    const float* __restrict__ W2, const float* __restrict__ b2,
    float* __restrict__ table)
{
    __shared__ float feats[FIN];
    __shared__ float hbuf2[HIDDEN];
    __shared__ float part2[4][33];

    const int t = threadIdx.x;
    const int o = t & 31;
    const int c = t >> 5;

    float4 w1r[32];
    {
        const float4* w1v = (const float4*)(W1 + t * FIN);
        #pragma unroll
        for (int k = 0; k < 32; ++k) w1r[k] = w1v[k];
    }
    float4 w2r[8];
    {
        const float4* w2v = (const float4*)(W2 + o * HIDDEN + c * 32);
        #pragma unroll
        for (int k = 0; k < 8; ++k) w2r[k] = w2v[k];
    }
    const float b1t = b1[t];
    const float b2o = b2[o];
    const float myfreq = (t < FIN) ? freqs[t & 15] : 0.0f;

    for (int pp = 0; pp < 8; ++pp) {
        const int pair = blockIdx.x * 8 + pp;
        if (pair >= NPAIRS_TBL) break;
        const float dr = (float)(pair / NOFF - (NOFF / 2));
        const float dc = (float)(pair % NOFF - (NOFF / 2));

        if (t < FIN) {
            const int g = t >> 4;
            float bse;
            switch (g >> 1) {
                case 0:  bse = dr;      break;
                case 1:  bse = dc;      break;
                case 2:  bse = dr + dc; break;
                default: bse = dr - dc; break;
            }
            const float arg = bse * myfreq;
            feats[t] = (g & 1) ? cosf(arg) : sinf(arg);
        }
        __syncthreads();

        float a0 = 0.f, a1 = 0.f, a2 = 0.f, a3 = 0.f;
        const float4* f4 = (const float4*)feats;
        #pragma unroll
        for (int k = 0; k < 32; k += 2) {
            float4 fa = f4[k], fb = f4[k + 1];
            a0 = fmaf(w1r[k].x,     fa.x, a0); a1 = fmaf(w1r[k].y,     fa.y, a1);
            a2 = fmaf(w1r[k].z,     fa.z, a2); a3 = fmaf(w1r[k].w,     fa.w, a3);
            a0 = fmaf(w1r[k + 1].x, fb.x, a0); a1 = fmaf(w1r[k + 1].y, fb.y, a1);
            a2 = fmaf(w1r[k + 1].z, fb.z, a2); a3 = fmaf(w1r[k + 1].w, fb.w, a3);
        }
        const float pre = (a0 + a1) + (a2 + a3) + b1t;
        hbuf2[t] = pre / (1.0f + expf(-pre));
        __syncthreads();

        float s0 = 0.f, s1 = 0.f, s2 = 0.f, s3 = 0.f;
        const float4* h4 = (const float4*)(hbuf2 + c * 32);
        #pragma unroll
        for (int k = 0; k < 8; k += 2) {
            float4 ha = h4[k], hb = h4[k + 1];
            s0 = fmaf(w2r[k].x,     ha.x, s0); s1 = fmaf(w2r[k].y,     ha.y, s1);
            s2 = fmaf(w2r[k].z,     ha.z, s2); s3 = fmaf(w2r[k].w,     ha.w, s3);
            s0 = fmaf(w2r[k + 1].x, hb.x, s0); s1 = fmaf(w2r[k + 1].y, hb.y, s1);
            s2 = fmaf(w2r[k + 1].z, hb.z, s2); s3 = fmaf(w2r[k + 1].w, hb.w, s3);
        }
        float s = (s0 + s1) + (s2 + s3);
        s += __shfl_xor(s, 32);
        if ((t & 63) < 32) part2[t >> 6][o] = s;
        __syncthreads();
        if (t < TOUT) {
            const float r = part2[0][t] + part2[1][t] + part2[2][t] + part2[3][t] + b2o;
            table[pair * TOUT + t] = r * 0.17677669529663687f;
        }
        __syncthreads();
    }
}

// ---------------------------------------------------------------------------
// Gather: dr/dc derived exactly from the flat index; only HBM traffic is the
// 128 MiB coalesced float4 output stream; table stays L2-resident.
__global__ __launch_bounds__(256) void gab_gather_kernel(
    const float* __restrict__ table,
    float4* __restrict__ out, int npairs)
{
    const int total = npairs * 8;
    const int stride = gridDim.x * blockDim.x;
    const float4* __restrict__ tbl4 = (const float4*)table;

    for (int idx = blockIdx.x * blockDim.x + threadIdx.x; idx < total; idx += stride) {
        const int p = idx >> 3;
        const int l = idx & 7;
        const int i = p >> 10;
        const int j = p & 1023;
        const int ir = (i >> 5) - (j >> 5) + (NOFF / 2);
        const int ic = (i & 31) - (j & 31) + (NOFF / 2);
        out[idx] = tbl4[(ir * NOFF + ic) * (TOUT / 4) + l];
    }
}

// ---------------------------------------------------------------------------
extern "C" void kernel_launch(void* const* d_in, const int* in_sizes, int n_in,
                              void* d_out, int out_size, void* d_ws, size_t ws_size,
                              hipStream_t stream) {
    // inputs: 0 seq_len 1 freqs(16) 2 W1(256*128) 3 b1(256) 4 W2(32*256)
    //         5 b2(32) 6 dr(S*S) 7 dc(S*S)
    const float* freqs = (const float*)d_in[1];
    const float* W1    = (const float*)d_in[2];
    const float* b1    = (const float*)d_in[3];
    const float* W2    = (const float*)d_in[4];
    const float* b2    = (const float*)d_in[5];
    float* out = (float*)d_out;

    const int npairs = in_sizes[6];                // S*S = 1024*1024

    // ws layout: [table 508 KB][P 385 KB]
    const size_t TBL_B = (size_t)NPAIRS_TBL * TOUT * 4;     // 508,032 B
    const size_t P_B   = (size_t)PROWS * HIDDEN * 4;        // 385,024 B
    float* table = (float*)d_ws;

    if (ws_size >= TBL_B + P_B) {
        float* P = (float*)((char*)d_ws + TBL_B);
        gab_ptab_kernel <<<PROWS, 256, 0, stream>>>(freqs, W1, P);
        gab_table_kernel<<<NBLK, 256, 0, stream>>>(P, b1, W2, b2, table);
    } else {
        gab_table_fallback<<<(NPAIRS_TBL + 7) / 8, 256, 0, stream>>>(freqs, W1, b1, W2, b2, table);
    }

    gab_gather_kernel<<<2048, 256, 0, stream>>>(table, (float4*)out, npairs);
}

// Round 7
// 40.157 us; speedup vs baseline: 3.7627x; 1.0348x over previous
//
#include <hip/hip_runtime.h>
#include <math.h>

// Problem constants (reference: POS_LEN=32, NUM_F=16, HIDDEN=256, T=32)
#define NUM_F   16
#define FIN     (8 * NUM_F)      // 128 fourier features
#define HIDDEN  256
#define TOUT    32
#define NOFF    63               // distinct offset values: -31..31
#define NSUM    125              // distinct dr+dc / dr-dc values: -62..62
#define NPAIRS_TBL (NOFF * NOFF) // 3969
#define PROWS   (NOFF + NOFF + NSUM + NSUM)      // 376 rows in P

// ---------------------------------------------------------------------------
// KP: layer-1 separable partials P[rho][h] (see R6). 48 blocks:
//   g0: rho 0..62    (Pa, chunks 0..7)    g1: rho 63..125  (Pb, chunks 8..15)
//   g2: rho 126..250 (Pp, chunks 16..31)  g3: rho 251..375 (Pm, chunks 32..47)
// Each block: W1 column-chunk g (32 floats/thread) loaded ONCE into VGPRs,
// feats for all <=8 rows precomputed in LDS (1 barrier), then 8x dot-32.
__global__ __launch_bounds__(256) void gab_ptab_kernel(
    const float* __restrict__ freqs, const float* __restrict__ W1,
    float* __restrict__ P)
{
    __shared__ float fv_all[8][32];

    const int b = blockIdx.x;
    int g, c;
    if (b < 8)       { g = 0; c = b; }
    else if (b < 16) { g = 1; c = b - 8; }
    else if (b < 32) { g = 2; c = b - 16; }
    else             { g = 3; c = b - 32; }
    const int nrows   = (g < 2) ? NOFF : NSUM;
    const int rowbase = (g == 0) ? 0 : (g == 1) ? NOFF
                      : (g == 2) ? 2 * NOFF : 2 * NOFF + NSUM;
    const int voff    = (g < 2) ? 31 : 62;

    const int t = threadIdx.x;

    // feats for the block's rows: thread t -> row t>>5, element t&31
    {
        const int r  = t >> 5;
        const int e  = t & 31;
        const int gr = c * 8 + r;
        if (gr < nrows) {
            const float arg = (float)(gr - voff) * freqs[e & 15];
            fv_all[r][e] = (e < 16) ? sinf(arg) : cosf(arg);
        }
    }

    // W1 row t, column block g -> 8 float4 VGPRs (one-time, amortized 8 rows)
    float4 w1c[8];
    {
        const float4* w4 = (const float4*)(W1 + t * FIN + g * 32);
        #pragma unroll
        for (int k = 0; k < 8; ++k) w1c[k] = w4[k];
    }
    __syncthreads();

    #pragma unroll
    for (int r = 0; r < 8; ++r) {
        const int gr = c * 8 + r;
        if (gr >= nrows) break;                 // uniform: no barriers below
        const float4* f4 = (const float4*)fv_all[r];  // same-addr broadcast
        float a0 = 0.f, a1 = 0.f, a2 = 0.f, a3 = 0.f;
        #pragma unroll
        for (int k = 0; k < 8; k += 2) {
            const float4 fa = f4[k], fb = f4[k + 1];
            a0 = fmaf(w1c[k].x,     fa.x, a0); a1 = fmaf(w1c[k].y,     fa.y, a1);
            a2 = fmaf(w1c[k].z,     fa.z, a2); a3 = fmaf(w1c[k].w,     fa.w, a3);
            a0 = fmaf(w1c[k + 1].x, fb.x, a0); a1 = fmaf(w1c[k + 1].y, fb.y, a1);
            a2 = fmaf(w1c[k + 1].z, fb.z, a2); a3 = fmaf(w1c[k + 1].w, fb.w, a3);
        }
        P[(rowbase + gr) * HIDDEN + t] = (a0 + a1) + (a2 + a3);
    }
}

// ---------------------------------------------------------------------------
// KT: one WAVE per pair — zero barriers, zero LDS allocations.
// Lane l: h[4l..4l+3] = silu(Pa[ia]+Pb[ib]+Pp[ip]+Pm[im]+b1) (coalesced f4);
// layer 2: acc[o] += W2[o][4l..4l+3].h4 (32 coalesced row loads, L1-hot);
// vector-halving shuffle reduce (masks 1,2,4,8,16, then xor-32) leaves
// lane l holding total for o = bitrev5(l&31); lanes <32 scatter-store.
__global__ __launch_bounds__(256) void gab_table_kernel(
    const float* __restrict__ P, const float* __restrict__ b1,
    const float* __restrict__ W2, const float* __restrict__ b2,
    float* __restrict__ table)
{
    const int pair = blockIdx.x * 4 + (threadIdx.x >> 6);
    if (pair >= NPAIRS_TBL) return;
    const int l = threadIdx.x & 63;

    const int ia = pair / NOFF;               // dr + 31
    const int ib = pair % NOFF;               // dc + 31
    const int ip = ia + ib;                   // (dr+dc) + 62
    const int im = ia - ib + 62;              // (dr-dc) + 62

    const float4* __restrict__ P4 = (const float4*)P;
    const float4 pa = P4[(0 * NOFF              + ia) * 64 + l];
    const float4 pb = P4[(1 * NOFF              + ib) * 64 + l];
    const float4 pp = P4[(2 * NOFF              + ip) * 64 + l];
    const float4 pm = P4[((2 * NOFF + NSUM)     + im) * 64 + l];
    const float4 bb = ((const float4*)b1)[l];

    float h0 = pa.x + pb.x + pp.x + pm.x + bb.x;
    float h1 = pa.y + pb.y + pp.y + pm.y + bb.y;
    float h2 = pa.z + pb.z + pp.z + pm.z + bb.z;
    float h3 = pa.w + pb.w + pp.w + pm.w + bb.w;
    h0 = h0 / (1.0f + expf(-h0));
    h1 = h1 / (1.0f + expf(-h1));
    h2 = h2 / (1.0f + expf(-h2));
    h3 = h3 / (1.0f + expf(-h3));

    // layer 2 partials: acc[o] over this lane's 4 h-values
    float acc[32];
    const float4* __restrict__ W24 = (const float4*)W2;
    #pragma unroll
    for (int o = 0; o < 32; ++o) {
        const float4 w = W24[o * 64 + l];     // coalesced: lane l -> cols 4l..4l+3
        acc[o] = fmaf(w.x, h0, fmaf(w.y, h1, fmaf(w.z, h2, w.w * h3)));
    }

    // vector-halving reduce: after step m, vector size halves; all static idx.
    #pragma unroll
    for (int i = 0; i < 16; ++i) {
        const float keep = (l & 1) ? acc[i + 16] : acc[i];
        const float send = (l & 1) ? acc[i] : acc[i + 16];
        acc[i] = keep + __shfl_xor(send, 1);
    }
    #pragma unroll
    for (int i = 0; i < 8; ++i) {
        const float keep = (l & 2) ? acc[i + 8] : acc[i];
        const float send = (l & 2) ? acc[i] : acc[i + 8];
        acc[i] = keep + __shfl_xor(send, 2);
    }
    #pragma unroll
    for (int i = 0; i < 4; ++i) {
        const float keep = (l & 4) ? acc[i + 4] : acc[i];
        const float send = (l & 4) ? acc[i] : acc[i + 4];
        acc[i] = keep + __shfl_xor(send, 4);
    }
    #pragma unroll
    for (int i = 0; i < 2; ++i) {
        const float keep = (l & 8) ? acc[i + 2] : acc[i];
        const float send = (l & 8) ? acc[i] : acc[i + 2];
        acc[i] = keep + __shfl_xor(send, 8);
    }
    {
        const float keep = (l & 16) ? acc[1] : acc[0];
        const float send = (l & 16) ? acc[0] : acc[1];
        acc[0] = keep + __shfl_xor(send, 16);
    }
    const float tot = acc[0] + __shfl_xor(acc[0], 32);

    if (l < 32) {
        // lane l holds output o = bitrev5(l)
        const int o = ((l & 1) << 4) | ((l & 2) << 2) | (l & 4)
                    | ((l & 8) >> 2) | ((l & 16) >> 4);
        table[pair * TOUT + o] = (tot + b2[o]) * 0.17677669529663687f; // /sqrt(32)
    }
}

// ---------------------------------------------------------------------------
// Fallback: R2's fully-fused table kernel (used only if ws too small).
__global__ __launch_bounds__(256, 2) void gab_table_fallback(
    const float* __restrict__ freqs,
    const float* __restrict__ W1, const float* __restrict__ b1,
    const float* __restrict__ W2, const float* __restrict__ b2,
    float* __restrict__ table)
{
    __shared__ float feats[FIN];
    __shared__ float hbuf2[HIDDEN];
    __shared__ float part2[4][33];

    const int t = threadIdx.x;
    const int o = t & 31;
    const int c = t >> 5;

    float4 w1r[32];
    {
        const float4* w1v = (const float4*)(W1 + t * FIN);
        #pragma unroll
        for (int k = 0; k < 32; ++k) w1r[k] = w1v[k];
    }
    float4 w2r[8];
    {
        const float4* w2v = (const float4*)(W2 + o * HIDDEN + c * 32);
        #pragma unroll
        for (int k = 0; k < 8; ++k) w2r[k] = w2v[k];
    }
    const float b1t = b1[t];
    const float b2o = b2[o];
    const float myfreq = (t < FIN) ? freqs[t & 15] : 0.0f;

    for (int pp = 0; pp < 8; ++pp) {
        const int pair = blockIdx.x * 8 + pp;
        if (pair >= NPAIRS_TBL) break;
        const float dr = (float)(pair / NOFF - (NOFF / 2));
        const float dc = (float)(pair % NOFF - (NOFF / 2));

        if (t < FIN) {
            const int g = t >> 4;
            float bse;
            switch (g >> 1) {
                case 0:  bse = dr;      break;
                case 1:  bse = dc;      break;
                case 2:  bse = dr + dc; break;
                default: bse = dr - dc; break;
            }
            const float arg = bse * myfreq;
            feats[t] = (g & 1) ? cosf(arg) : sinf(arg);
        }
        __syncthreads();

        float a0 = 0.f, a1 = 0.f, a2 = 0.f, a3 = 0.f;
        const float4* f4 = (const float4*)feats;
        #pragma unroll
        for (int k = 0; k < 32; k += 2) {
            float4 fa = f4[k], fb = f4[k + 1];
            a0 = fmaf(w1r[k].x,     fa.x, a0); a1 = fmaf(w1r[k].y,     fa.y, a1);
            a2 = fmaf(w1r[k].z,     fa.z, a2); a3 = fmaf(w1r[k].w,     fa.w, a3);
            a0 = fmaf(w1r[k + 1].x, fb.x, a0); a1 = fmaf(w1r[k + 1].y, fb.y, a1);
            a2 = fmaf(w1r[k + 1].z, fb.z, a2); a3 = fmaf(w1r[k + 1].w, fb.w, a3);
        }
        const float pre = (a0 + a1) + (a2 + a3) + b1t;
        hbuf2[t] = pre / (1.0f + expf(-pre));
        __syncthreads();

        float s0 = 0.f, s1 = 0.f, s2 = 0.f, s3 = 0.f;
        const float4* h4 = (const float4*)(hbuf2 + c * 32);
        #pragma unroll
        for (int k = 0; k < 8; k += 2) {
            float4 ha = h4[k], hb = h4[k + 1];
            s0 = fmaf(w2r[k].x,     ha.x, s0); s1 = fmaf(w2r[k].y,     ha.y, s1);
            s2 = fmaf(w2r[k].z,     ha.z, s2); s3 = fmaf(w2r[k].w,     ha.w, s3);
            s0 = fmaf(w2r[k + 1].x, hb.x, s0); s1 = fmaf(w2r[k + 1].y, hb.y, s1);
            s2 = fmaf(w2r[k + 1].z, hb.z, s2); s3 = fmaf(w2r[k + 1].w, hb.w, s3);
        }
        float s = (s0 + s1) + (s2 + s3);
        s += __shfl_xor(s, 32);
        if ((t & 63) < 32) part2[t >> 6][o] = s;
        __syncthreads();
        if (t < TOUT) {
            const float r = part2[0][t] + part2[1][t] + part2[2][t] + part2[3][t] + b2o;
            table[pair * TOUT + t] = r * 0.17677669529663687f;
        }
        __syncthreads();
    }
}

// ---------------------------------------------------------------------------
// Gather: dr/dc derived exactly from the flat index; only HBM traffic is the
// 128 MiB coalesced float4 output stream; table stays L2-resident.
__global__ __launch_bounds__(256) void gab_gather_kernel(
    const float* __restrict__ table,
    float4* __restrict__ out, int npairs)
{
    const int total = npairs * 8;
    const int stride = gridDim.x * blockDim.x;
    const float4* __restrict__ tbl4 = (const float4*)table;

    for (int idx = blockIdx.x * blockDim.x + threadIdx.x; idx < total; idx += stride) {
        const int p = idx >> 3;
        const int l = idx & 7;
        const int i = p >> 10;
        const int j = p & 1023;
        const int ir = (i >> 5) - (j >> 5) + (NOFF / 2);
        const int ic = (i & 31) - (j & 31) + (NOFF / 2);
        out[idx] = tbl4[(ir * NOFF + ic) * (TOUT / 4) + l];
    }
}

// ---------------------------------------------------------------------------
extern "C" void kernel_launch(void* const* d_in, const int* in_sizes, int n_in,
                              void* d_out, int out_size, void* d_ws, size_t ws_size,
                              hipStream_t stream) {
    // inputs: 0 seq_len 1 freqs(16) 2 W1(256*128) 3 b1(256) 4 W2(32*256)
    //         5 b2(32) 6 dr(S*S) 7 dc(S*S)
    const float* freqs = (const float*)d_in[1];
    const float* W1    = (const float*)d_in[2];
    const float* b1    = (const float*)d_in[3];
    const float* W2    = (const float*)d_in[4];
    const float* b2    = (const float*)d_in[5];
    float* out = (float*)d_out;

    const int npairs = in_sizes[6];                // S*S = 1024*1024

    // ws layout: [table 508 KB][P 385 KB]
    const size_t TBL_B = (size_t)NPAIRS_TBL * TOUT * 4;     // 508,032 B
    const size_t P_B   = (size_t)PROWS * HIDDEN * 4;        // 385,024 B
    float* table = (float*)d_ws;

    if (ws_size >= TBL_B + P_B) {
        float* P = (float*)((char*)d_ws + TBL_B);
        gab_ptab_kernel <<<48, 256, 0, stream>>>(freqs, W1, P);
        gab_table_kernel<<<(NPAIRS_TBL + 3) / 4, 256, 0, stream>>>(P, b1, W2, b2, table);
    } else {
        gab_table_fallback<<<(NPAIRS_TBL + 7) / 8, 256, 0, stream>>>(freqs, W1, b1, W2, b2, table);
    }

    gab_gather_kernel<<<2048, 256, 0, stream>>>(table, (float4*)out, npairs);
}